// Round 1
// baseline (992.410 us; speedup 1.0000x reference)
//
#include <hip/hip_runtime.h>
#include <stdint.h>

// ContextAttention: B=4, S=4096, D=512.
// Round 10: qkt ported to the 256^2 8-phase counted-vmcnt schedule (T3+T4)
// with LDS XOR swizzle (T2), setprio (T5), XCD swizzle (T1). 512 thr, 8 waves
// (2Mx4N), BK=64, 128KB dynamic LDS (2 dbuf x [A,B] x [k0,k1] x 256x32 bf16).
// Staging unit = one 256x32 k-half (2x global_load_lds w16/thread). vmcnt(4)
// once per K-tile slot (vmcnt(0) in last 2 slots where stages are skipped).
// proj_fast / pv_kernel / convert unchanged (m97-style core).
// BANNED: __launch_bounds__ (crash-assoc rounds 1-3). All grids 1-D.

#define BDIM 4
#define SDIM 4096
#define DDIM 512
#define MROWS (BDIM * SDIM)  // 16384
#define XB_ELEMS ((size_t)MROWS * DDIM)        // 8388608
#define W_ELEMS ((size_t)DDIM * DDIM)          // 262144
#define KT8 8                                  // 512 / 64 K-tiles (qkt8)

typedef short short8_t __attribute__((ext_vector_type(8)));
typedef short short4_t __attribute__((ext_vector_type(4)));
typedef float float4_t __attribute__((ext_vector_type(4)));

typedef __attribute__((address_space(1))) void gvoid_t;
typedef __attribute__((address_space(3))) void lvoid_t;

__device__ __forceinline__ short f2bf(float f) {
    union { float f; uint32_t u; } v; v.f = f;
    uint32_t r = v.u + 0x7FFFu + ((v.u >> 16) & 1u);  // RNE
    return (short)(r >> 16);
}
__device__ __forceinline__ float bf2f(short s) {
    union { uint32_t u; float f; } v; v.u = ((uint32_t)(uint16_t)s) << 16;
    return v.f;
}

// Storage-dtype vote (proven).
__global__ void detect_kernel(const uint32_t* __restrict__ tok, int* __restrict__ flag) {
    __shared__ int red[256];
    const int tid = threadIdx.x;
    int c = 0;
    for (int i = tid; i < 4096; i += 256) {
        uint32_t e = (tok[i] >> 7) & 0xFFu;
        c += (e >= 105u && e <= 135u) ? 1 : 0;
    }
    red[tid] = c;
    __syncthreads();
    for (int s = 128; s > 0; s >>= 1) {
        if (tid < s) red[tid] += red[tid + s];
        __syncthreads();
    }
    if (tid == 0) *flag = (red[0] > 2048) ? 1 : 0;  // 1 = bf16 storage
}

__global__ void zero_rs_kernel(float* __restrict__ RS) {
    RS[blockIdx.x * 256 + threadIdx.x] = 0.f;
}

// Pre-convert inputs to bf16: dst = Xb[8388608] | W1b | W2b | W3b (262144 ea).
__global__ void convert_kernel(const void* __restrict__ X, const void* __restrict__ W1,
                               const void* __restrict__ W2, const void* __restrict__ W3,
                               short* __restrict__ dst, const int* __restrict__ flagp)
{
    const int bf16in = *flagp;
    const size_t i4 = ((size_t)blockIdx.x * 256 + threadIdx.x) * 4;  // elem index
    const void* src; size_t off;
    if (i4 < XB_ELEMS) { src = X; off = i4; }
    else {
        const size_t j = i4 - XB_ELEMS;
        const int g = (int)(j / W_ELEMS);
        src = (g == 0) ? W1 : (g == 1) ? W2 : W3;
        off = j - (size_t)g * W_ELEMS;
    }
    if (bf16in) {
        *(short4_t*)(dst + i4) = *(const short4_t*)((const short*)src + off);
    } else {
        float4 v = *(const float4*)((const float*)src + off);
        short4_t s = { f2bf(v.x), f2bf(v.y), f2bf(v.z), f2bf(v.w) };
        *(short4_t*)(dst + i4) = s;
    }
}

// ---------------- shared m97-style GEMM core (proj / pv) ----------------
// 128x128 tile, BK=32, unpadded LDS [128][32], staged via global_load_lds
// width=16 (wave-uniform LDS base + lane*16 == row-major 16-row chunk).
__device__ __forceinline__ void gemm_core(
    const short* __restrict__ A, int lda,
    const short* __restrict__ B, int ldb,
    int m0, int n0, int kIters,
    short* As, short* Bs, float4_t acc[4][4])
{
    const int tid = threadIdx.x;
    const int w = tid >> 6, lane = tid & 63, quad = lane >> 4, l16 = lane & 15;
    const int wm = w >> 1, wn = w & 1;
    const int rsub = lane >> 2;          // row within 16-row chunk
    const int col8 = 8 * (lane & 3);     // 8-elem (16B) column chunk

    for (int kk = 0; kk < kIters; ++kk) {
        const int k0 = 32 * kk;
        __syncthreads();
#pragma unroll
        for (int c = 0; c < 2; ++c) {
            const int row = 32 * w + 16 * c + rsub;
            const short* g = A + (size_t)(m0 + row) * lda + k0 + col8;
            __builtin_amdgcn_global_load_lds((const gvoid_t*)g,
                (lvoid_t*)(As + (32 * w + 16 * c) * 32), 16, 0, 0);
        }
#pragma unroll
        for (int c = 0; c < 2; ++c) {
            const int row = 32 * w + 16 * c + rsub;
            const short* g = B + (size_t)(n0 + row) * ldb + k0 + col8;
            __builtin_amdgcn_global_load_lds((const gvoid_t*)g,
                (lvoid_t*)(Bs + (32 * w + 16 * c) * 32), 16, 0, 0);
        }
        __syncthreads();

        short8_t af[4], bfr[4];
#pragma unroll
        for (int mt = 0; mt < 4; ++mt)
            af[mt] = *(const short8_t*)&As[(64 * wm + 16 * mt + l16) * 32 + 8 * quad];
#pragma unroll
        for (int nt = 0; nt < 4; ++nt)
            bfr[nt] = *(const short8_t*)&Bs[(64 * wn + 16 * nt + l16) * 32 + 8 * quad];
#pragma unroll
        for (int mt = 0; mt < 4; ++mt)
#pragma unroll
            for (int nt = 0; nt < 4; ++nt)
                acc[mt][nt] = __builtin_amdgcn_mfma_f32_16x16x32_bf16(af[mt], bfr[nt], acc[mt][nt], 0, 0, 0);
    }
}

// ---------------- proj (all-bf16 via Xb/Wb) ----------------
// g=0: Q = Xb @ W1b^T; g=1: K; g=2: Vt[m=e][n=bs] = W3b @ Xb^T.
__global__ void proj_fast(const short* __restrict__ XbWb, short* __restrict__ QKV)
{
    __shared__ __align__(16) short As[128 * 32];
    __shared__ __align__(16) short Bs[128 * 32];

    const short* Xb = XbWb;
    const int bid = blockIdx.x;
    const int g = bid >> 9;
    const int r = bid & 511;

    const short* Ap; const short* Bp; short* Op;
    int m0, n0, ldo;
    if (g == 2) {
        Ap = XbWb + XB_ELEMS + 2 * W_ELEMS; Bp = Xb;
        Op = QKV + 2 * (size_t)MROWS * DDIM;
        m0 = 128 * (r & 3); n0 = 128 * (r >> 2); ldo = MROWS;   // Vt[e][bs]
    } else {
        Ap = Xb; Bp = XbWb + XB_ELEMS + (size_t)g * W_ELEMS;
        Op = QKV + (size_t)g * MROWS * DDIM;
        m0 = 128 * (r >> 2); n0 = 128 * (r & 3); ldo = DDIM;    // Q/K[bs][e]
    }

    const float4_t z4 = {0.f, 0.f, 0.f, 0.f};
    float4_t acc[4][4];
#pragma unroll
    for (int i = 0; i < 4; ++i)
#pragma unroll
        for (int j = 0; j < 4; ++j) acc[i][j] = z4;

    gemm_core(Ap, DDIM, Bp, DDIM, m0, n0, 16, As, Bs, acc);

    const int tid = threadIdx.x;
    const int w = tid >> 6, lane = tid & 63, quad = lane >> 4, l16 = lane & 15;
    const int wm = w >> 1, wn = w & 1;
#pragma unroll
    for (int mt = 0; mt < 4; ++mt)
#pragma unroll
        for (int nt = 0; nt < 4; ++nt)
#pragma unroll
            for (int rr = 0; rr < 4; ++rr) {
                const int m = m0 + 64 * wm + 16 * mt + 4 * quad + rr;
                const int n = n0 + 64 * wn + 16 * nt + l16;
                Op[(size_t)m * ldo + n] = f2bf(acc[mt][nt][rr]);
            }
}

// ---------------- qkt8: 256^2 8-phase P = exp(sc * Q K^T) + rowsums ----------
// 512 threads, 8 waves (2Mx4N), BK=64. Dynamic LDS 128KB:
//   region(d, ab, kh) = lds + (d*4 + ab*2 + kh)*8192 shorts  ([256 rows][32 k])
// Stage schedule per slot t (reading buf d=t&1):
//   ph0: (t+1,A,k1)  ph1: (t+1,B,k1)  ph2: (t+2,A,k0)  ph3: (t+2,B,k0)
// vmcnt(4) before slot-end barrier (vmcnt(0) when t>=KT8-2: stages skipped).
// Swizzle (involution, byte ^= ((row>>1)&3)<<4): stage uses pre-swizzled
// global source granule, reads use swizzled granule -> 2-way (free) banks.
__global__ void qkt8_kernel(const short* __restrict__ QKV, short* __restrict__ P,
                            float* __restrict__ RS, int bbase)
{
    extern __shared__ short lds[];

    const int cpx = (int)(gridDim.x >> 3);          // grid % 8 == 0 (bijective)
    const int bid = (int)blockIdx.x;
    const int l = (bid & 7) * cpx + (bid >> 3);     // XCD swizzle (T1)
    const int bb = l >> 8;
    const int r = l & 255;
    const int b = bbase + bb;
    const int m0 = 256 * (r >> 4);
    const int n0 = 256 * (r & 15);

    const short* Qb = QKV + (size_t)b * SDIM * DDIM;
    const short* Kb = QKV + (size_t)MROWS * DDIM + (size_t)b * SDIM * DDIM;

    const int tid = (int)threadIdx.x;
    const int w = tid >> 6, lane = tid & 63;
    const int quad = lane >> 4, l16 = lane & 15;
    const int wm = w >> 2, wn = w & 3;              // 2M x 4N wave grid
    const int xsw = (l16 >> 1) & 3;                 // read swizzle key (lane-const)
    const int sg = (lane & 3) ^ ((lane >> 3) & 3);  // stage source granule

    // stage one 256x32 k-half unit: u = K-tile, ab: 0=A(Q) 1=B(K), kh = k-half
    auto STAGE = [&](int u, int ab, int kh) {
        if (u >= KT8) return;
        const short* gb = ab ? Kb : Qb;
        const int r0 = ab ? n0 : m0;
        short* rg = lds + (size_t)((u & 1) * 4 + ab * 2 + kh) * 8192;
#pragma unroll
        for (int j = 0; j < 2; ++j) {
            const int row = j * 128 + 16 * w + (lane >> 2);
            const short* g = gb + (size_t)(r0 + row) * DDIM + u * 64 + kh * 32 + 8 * sg;
            __builtin_amdgcn_global_load_lds((const gvoid_t*)g,
                (lvoid_t*)(rg + (j * 128 + 16 * w) * 32), 16, 0, 0);
        }
    };

    const float4_t z4 = {0.f, 0.f, 0.f, 0.f};
    float4_t acc[8][4];
#pragma unroll
    for (int i = 0; i < 8; ++i)
#pragma unroll
        for (int j = 0; j < 4; ++j) acc[i][j] = z4;

    // Prologue: K-tile 0 complete + K-tile 1 k0-halves; allow newest 2 units
    // (4 loads) outstanding -> t0 fully landed, t1.k0 landed by slot-0 end.
    STAGE(0, 0, 0); STAGE(0, 1, 0); STAGE(0, 0, 1); STAGE(0, 1, 1);
    STAGE(1, 0, 0); STAGE(1, 1, 0);
    asm volatile("s_waitcnt vmcnt(4)" ::: "memory");
    __builtin_amdgcn_s_barrier();

    short8_t af[8];
    for (int t = 0; t < KT8; ++t) {
        const int d = t & 1;
#pragma unroll
        for (int ks = 0; ks < 2; ++ks) {
            const short* Ar = lds + (size_t)(d * 4 + ks) * 8192;
            const short* Br = lds + (size_t)(d * 4 + 2 + ks) * 8192;
#pragma unroll
            for (int nh = 0; nh < 2; ++nh) {
                if (nh == 0) {
#pragma unroll
                    for (int mt = 0; mt < 8; ++mt)
                        af[mt] = *(const short8_t*)&Ar[(128 * wm + 16 * mt + l16) * 32 + 8 * (quad ^ xsw)];
                }
                const short8_t bf0 = *(const short8_t*)&Br[(64 * wn + 32 * nh + l16) * 32 + 8 * (quad ^ xsw)];
                const short8_t bf1 = *(const short8_t*)&Br[(64 * wn + 32 * nh + 16 + l16) * 32 + 8 * (quad ^ xsw)];
                const int ph = ks * 2 + nh;
                if (ph == 0)      STAGE(t + 1, 0, 1);
                else if (ph == 1) STAGE(t + 1, 1, 1);
                else if (ph == 2) STAGE(t + 2, 0, 0);
                else              STAGE(t + 2, 1, 0);
                __builtin_amdgcn_s_barrier();
                __builtin_amdgcn_s_setprio(1);
#pragma unroll
                for (int mt = 0; mt < 8; ++mt) {
                    acc[mt][2 * nh + 0] = __builtin_amdgcn_mfma_f32_16x16x32_bf16(af[mt], bf0, acc[mt][2 * nh + 0], 0, 0, 0);
                    acc[mt][2 * nh + 1] = __builtin_amdgcn_mfma_f32_16x16x32_bf16(af[mt], bf1, acc[mt][2 * nh + 1], 0, 0, 0);
                }
                __builtin_amdgcn_s_setprio(0);
                if (ph == 3) {
                    if (t < KT8 - 2) asm volatile("s_waitcnt vmcnt(4)" ::: "memory");
                    else             asm volatile("s_waitcnt vmcnt(0)" ::: "memory");
                }
                __builtin_amdgcn_s_barrier();
            }
        }
    }

    // Epilogue: P = exp2(acc * kSc) as bf16 + rowsum atomics (same math as r9).
    const float kSc = 1.44269504088896341f * 0.04419417382415922f;  // log2(e)/sqrt(512)
    short* Pb = P + (size_t)bb * SDIM * SDIM;
#pragma unroll
    for (int mt = 0; mt < 8; ++mt)
#pragma unroll
        for (int rr = 0; rr < 4; ++rr) {
            const int q = m0 + 128 * wm + 16 * mt + 4 * quad + rr;
            float sum = 0.f;
#pragma unroll
            for (int nt = 0; nt < 4; ++nt) {
                const float p = exp2f(acc[mt][nt][rr] * kSc);
                const short pb = f2bf(p);
                sum += bf2f(pb);
                Pb[(size_t)q * SDIM + n0 + 64 * wn + 16 * nt + l16] = pb;
            }
            sum += __shfl_xor(sum, 1); sum += __shfl_xor(sum, 2);
            sum += __shfl_xor(sum, 4); sum += __shfl_xor(sum, 8);
            if (l16 == 0) atomicAdd(&RS[(size_t)b * SDIM + q], sum);
        }
}

// ---------------- pv: out = (P @ Vt-rows) / RS ----------------
__global__ void pv_kernel(const short* __restrict__ P, const short* __restrict__ QKV,
                          const float* __restrict__ RS, void* __restrict__ out,
                          const int* __restrict__ flagp, int bbase)
{
    __shared__ __align__(16) short As[128 * 32];
    __shared__ __align__(16) short Bs[128 * 32];

    const int bf16out = *flagp;
    const int bid = blockIdx.x;
    const int bb = bid >> 7;
    const int r = bid & 127;
    const int b = bbase + bb;
    const int m0 = 128 * (r >> 2);
    const int n0 = 128 * (r & 3);

    const short* Pb = P + (size_t)bb * SDIM * SDIM;
    const short* Vt = QKV + 2 * (size_t)MROWS * DDIM + (size_t)b * SDIM;  // rows stride MROWS

    const float4_t z4 = {0.f, 0.f, 0.f, 0.f};
    float4_t acc[4][4];
#pragma unroll
    for (int i = 0; i < 4; ++i)
#pragma unroll
        for (int j = 0; j < 4; ++j) acc[i][j] = z4;

    gemm_core(Pb, SDIM, Vt, MROWS, m0, n0, 128, As, Bs, acc);

    const int tid = threadIdx.x;
    const int w = tid >> 6, lane = tid & 63, quad = lane >> 4, l16 = lane & 15;
    const int wm = w >> 1, wn = w & 1;
#pragma unroll
    for (int mt = 0; mt < 4; ++mt)
#pragma unroll
        for (int rr = 0; rr < 4; ++rr) {
            const size_t grow = (size_t)b * SDIM + m0 + 64 * wm + 16 * mt + 4 * quad + rr;
            const float inv = 1.0f / RS[grow];
#pragma unroll
            for (int nt = 0; nt < 4; ++nt) {
                const int n = n0 + 64 * wn + 16 * nt + l16;
                const float o = acc[mt][nt][rr] * inv;
                if (bf16out) ((short*)out)[grow * DDIM + n] = f2bf(o);
                else         ((float*)out)[grow * DDIM + n] = o;
            }
        }
}

// ---------------- Fallbacks (proven round-6/8 versions) ----------------
__global__ void proj_mfma_legacy(const void* __restrict__ X, const void* __restrict__ W1,
                          const void* __restrict__ W2, const void* __restrict__ W3,
                          short* __restrict__ QKV, const int* __restrict__ flagp)
{
    __shared__ __align__(16) short As[128][40];
    __shared__ __align__(16) short Bs[128][40];

    const int bf16in = *flagp;
    const int bid = blockIdx.x;
    const int g = bid >> 9;
    const int r = bid & 511;

    const void* Ap; const void* Bp; short* Op;
    int m0, n0, ldo;
    if (g == 2) {
        Ap = W3; Bp = X; Op = QKV + 2 * (size_t)MROWS * DDIM;
        m0 = 128 * (r & 3); n0 = 128 * (r >> 2); ldo = MROWS;
    } else {
        Ap = X; Bp = (g == 0) ? W1 : W2; Op = QKV + (size_t)g * MROWS * DDIM;
        m0 = 128 * (r >> 2); n0 = 128 * (r & 3); ldo = DDIM;
    }

    const float* Af = (const float*)Ap;  const float* Bf = (const float*)Bp;
    const short* Ah = (const short*)Ap;  const short* Bh = (const short*)Bp;

    const int tid = threadIdx.x;
    const int w = tid >> 6, lane = tid & 63, quad = lane >> 4, l16 = lane & 15;
    const int wm = w >> 1, wn = w & 1;
    const int rgrp = tid >> 3, cg = tid & 7;

    const float4_t z4 = {0.f, 0.f, 0.f, 0.f};
    float4_t acc[4][4];
#pragma unroll
    for (int i = 0; i < 4; ++i)
#pragma unroll
        for (int j = 0; j < 4; ++j) acc[i][j] = z4;

    for (int kk = 0; kk < 16; ++kk) {
        const int k0 = 32 * kk;
        __syncthreads();
        if (bf16in) {
#pragma unroll
            for (int i = 0; i < 4; ++i) {
                const int row = rgrp + 32 * i;
                *(short4_t*)&As[row][4 * cg] =
                    *(const short4_t*)(Ah + (size_t)(m0 + row) * DDIM + k0 + 4 * cg);
                *(short4_t*)&Bs[row][4 * cg] =
                    *(const short4_t*)(Bh + (size_t)(n0 + row) * DDIM + k0 + 4 * cg);
            }
        } else {
#pragma unroll
            for (int i = 0; i < 4; ++i) {
                const int row = rgrp + 32 * i;
                float4 va = *(const float4*)(Af + (size_t)(m0 + row) * DDIM + k0 + 4 * cg);
                short4_t sa = { f2bf(va.x), f2bf(va.y), f2bf(va.z), f2bf(va.w) };
                *(short4_t*)&As[row][4 * cg] = sa;
                float4 vb = *(const float4*)(Bf + (size_t)(n0 + row) * DDIM + k0 + 4 * cg);
                short4_t sb = { f2bf(vb.x), f2bf(vb.y), f2bf(vb.z), f2bf(vb.w) };
                *(short4_t*)&Bs[row][4 * cg] = sb;
            }
        }
        __syncthreads();

        short8_t af[4], bfr[4];
#pragma unroll
        for (int mt = 0; mt < 4; ++mt)
            af[mt] = *(const short8_t*)&As[64 * wm + 16 * mt + l16][8 * quad];
#pragma unroll
        for (int nt = 0; nt < 4; ++nt)
            bfr[nt] = *(const short8_t*)&Bs[64 * wn + 16 * nt + l16][8 * quad];
#pragma unroll
        for (int mt = 0; mt < 4; ++mt)
#pragma unroll
            for (int nt = 0; nt < 4; ++nt)
                acc[mt][nt] = __builtin_amdgcn_mfma_f32_16x16x32_bf16(af[mt], bfr[nt], acc[mt][nt], 0, 0, 0);
    }

#pragma unroll
    for (int mt = 0; mt < 4; ++mt)
#pragma unroll
        for (int nt = 0; nt < 4; ++nt)
#pragma unroll
            for (int rr = 0; rr < 4; ++rr) {
                const int m = m0 + 64 * wm + 16 * mt + 4 * quad + rr;
                const int n = n0 + 64 * wn + 16 * nt + l16;
                Op[(size_t)m * ldo + n] = f2bf(acc[mt][nt][rr]);
            }
}

__global__ void attn_mfma(const short* __restrict__ QKV, void* __restrict__ out,
                          const int* __restrict__ flagp)
{
    __shared__ __align__(16) short Ks[32][520];
    __shared__ __align__(16) short Ps[32][72];
    __shared__ float rowsum[2][32];

    const int bf16out = *flagp;
    const short* Qb = QKV;
    const short* Kb = QKV + (size_t)MROWS * DDIM;
    const short* Vt = QKV + 2 * (size_t)MROWS * DDIM;

    const int b = blockIdx.x >> 7;
    const int q0 = (blockIdx.x & 127) * 32;
    const int tid = threadIdx.x;
    const int w = tid >> 6, lane = tid & 63, quad = lane >> 4, l16 = lane & 15;
    const int strip = w >> 1, half = w & 1;

    short8_t qf[16];
    {
        const short* qrow = Qb + (size_t)(b * SDIM + q0 + 16 * strip + l16) * DDIM + 8 * quad;
#pragma unroll
        for (int kc = 0; kc < 16; ++kc)
            qf[kc] = *(const short8_t*)(qrow + 32 * kc);
    }

    const float4_t z4 = {0.f, 0.f, 0.f, 0.f};
    float4_t o[2][8];
#pragma unroll
    for (int mt = 0; mt < 2; ++mt)
#pragma unroll
        for (int nt = 0; nt < 8; ++nt) o[mt][nt] = z4;
    float rs[4] = {0.f, 0.f, 0.f, 0.f};

    const float kSc = 1.44269504088896341f * 0.04419417382415922f;

    for (int kt = 0; kt < 128; ++kt) {
        const int kv0 = 32 * kt;
        __syncthreads();
#pragma unroll
        for (int r = 0; r < 8; ++r) {
            const int kv = 8 * w + r;
            short8_t t = *(const short8_t*)(Kb + (size_t)(b * SDIM + kv0 + kv) * DDIM + 8 * lane);
            *(short8_t*)&Ks[kv][8 * lane] = t;
        }
        __syncthreads();

        float4_t sacc = z4;
#pragma unroll
        for (int kc = 0; kc < 16; ++kc) {
            short8_t kf = *(const short8_t*)&Ks[16 * half + l16][32 * kc + 8 * quad];
            sacc = __builtin_amdgcn_mfma_f32_16x16x32_bf16(qf[kc], kf, sacc, 0, 0, 0);
        }

#pragma unroll
        for (int r = 0; r < 4; ++r) {
            const float p = exp2f(sacc[r] * kSc);
            const short pb = f2bf(p);
            rs[r] += bf2f(pb);
            Ps[16 * strip + 4 * quad + r][16 * half + l16] = pb;
        }
        __syncthreads();

        short8_t pa0 = *(const short8_t*)&Ps[l16][8 * quad];
        short8_t pa1 = *(const short8_t*)&Ps[16 + l16][8 * quad];
#pragma unroll
        for (int nt = 0; nt < 8; ++nt) {
            const short* vp = Vt + (size_t)(128 * w + 16 * nt + l16) * MROWS
                            + (b * SDIM + kv0 + 8 * quad);
            short8_t vb = *(const short8_t*)vp;
            o[0][nt] = __builtin_amdgcn_mfma_f32_16x16x32_bf16(pa0, vb, o[0][nt], 0, 0, 0);
            o[1][nt] = __builtin_amdgcn_mfma_f32_16x16x32_bf16(pa1, vb, o[1][nt], 0, 0, 0);
        }
    }

#pragma unroll
    for (int r = 0; r < 4; ++r) {
        float v = rs[r];
        v += __shfl_xor(v, 1); v += __shfl_xor(v, 2);
        v += __shfl_xor(v, 4); v += __shfl_xor(v, 8);
        rs[r] = v;
    }
    if (l16 == 0) {
#pragma unroll
        for (int r = 0; r < 4; ++r)
            rowsum[half][16 * strip + 4 * quad + r] = rs[r];
    }
    __syncthreads();

#pragma unroll
    for (int mt = 0; mt < 2; ++mt)
#pragma unroll
        for (int r = 0; r < 4; ++r) {
            const int q = 16 * mt + 4 * quad + r;
            const float inv = 1.0f / (rowsum[0][q] + rowsum[1][q]);
            const size_t base = (size_t)(b * SDIM + q0 + q) * DDIM + 128 * w + l16;
            if (bf16out) {
                short* orow = (short*)out + base;
#pragma unroll
                for (int nt = 0; nt < 8; ++nt)
                    orow[16 * nt] = f2bf(o[mt][nt][r] * inv);
            } else {
                float* orow = (float*)out + base;
#pragma unroll
                for (int nt = 0; nt < 8; ++nt)
                    orow[16 * nt] = o[mt][nt][r] * inv;
            }
        }
}

__global__ void zero_out_kernel(short* __restrict__ out, int n) {
    int i = blockIdx.x * 256 + threadIdx.x;
    if (i < n) out[i] = 0;
}

extern "C" void kernel_launch(void* const* d_in, const int* in_sizes, int n_in,
                              void* d_out, int out_size, void* d_ws, size_t ws_size,
                              hipStream_t stream) {
    const void* token = d_in[0];
    const void* Wp[3] = { d_in[1], d_in[2], d_in[3] };
    {
        int wi = 0;
        const void* tk = nullptr; const void* ws3[3] = {nullptr, nullptr, nullptr};
        bool ok = true;
        for (int i = 0; i < n_in && i < 4; ++i) {
            if (in_sizes[i] == BDIM * SDIM * DDIM) { if (tk) ok = false; tk = d_in[i]; }
            else if (in_sizes[i] == DDIM * DDIM) { if (wi < 3) ws3[wi++] = d_in[i]; else ok = false; }
            else ok = false;
        }
        if (ok && tk && wi == 3) { token = tk; Wp[0] = ws3[0]; Wp[1] = ws3[1]; Wp[2] = ws3[2]; }
    }

    const size_t qkvBytes = 3 * (size_t)MROWS * DDIM * sizeof(short);  // 48 MB
    const size_t need_base = qkvBytes + 256;
    if (ws_size < need_base) {
        zero_out_kernel<<<(out_size + 255) / 256, 256, 0, stream>>>((short*)d_out, out_size);
        return;
    }

    short* QKV = (short*)d_ws;
    int* flag = (int*)((char*)d_ws + qkvBytes);
    short* P = (short*)((char*)d_ws + need_base);   // P slab; Xb/Wb overlap (dead before qkt)
    const size_t pElems1 = (size_t)SDIM * SDIM;

    int nb = 0;
    for (int cand = 4; cand >= 1; cand >>= 1) {
        const size_t need = need_base + (size_t)cand * pElems1 * sizeof(short)
                          + (size_t)MROWS * sizeof(float);
        if (ws_size >= need) { nb = cand; break; }
    }

    detect_kernel<<<1, 256, 0, stream>>>((const uint32_t*)token, flag);

    if (nb == 0) {
        proj_mfma_legacy<<<dim3(1536), 256, 0, stream>>>(token, Wp[0], Wp[1], Wp[2], QKV, flag);
        attn_mfma<<<dim3(512), 256, 0, stream>>>(QKV, d_out, flag);
        return;
    }

    // One-time: allow 128KB dynamic LDS for qkt8 (host-side, capture-safe).
    static bool qkt8_attr = false;
    if (!qkt8_attr) {
        (void)hipFuncSetAttribute(reinterpret_cast<const void*>(qkt8_kernel),
                                  hipFuncAttributeMaxDynamicSharedMemorySize, 131072);
        qkt8_attr = true;
    }

    // Xb|W1b|W2b|W3b live at the head of the P slab (18.35 MB <= 32 MB min slab).
    short* XbWb = P;
    const size_t cvt4 = (XB_ELEMS + 3 * W_ELEMS) / 4;  // 2293760 lanes
    convert_kernel<<<dim3((unsigned)(cvt4 / 256)), 256, 0, stream>>>(
        token, Wp[0], Wp[1], Wp[2], XbWb, flag);
    proj_fast<<<dim3(1536), 256, 0, stream>>>(XbWb, QKV);

    float* RS = (float*)(P + (size_t)nb * pElems1);
    zero_rs_kernel<<<dim3(MROWS / 256), 256, 0, stream>>>(RS);
    for (int p = 0; p < BDIM / nb; ++p) {
        const int bbase = p * nb;
        qkt8_kernel<<<dim3(nb * 256), 512, 131072, stream>>>(QKV, P, RS, bbase);
        pv_kernel<<<dim3(nb * 128), 256, 0, stream>>>(P, QKV, RS, d_out, flag, bbase);
    }
}

// Round 2
// 369.721 us; speedup vs baseline: 2.6842x; 2.6842x over previous
//
#include <hip/hip_runtime.h>
#include <stdint.h>

// ContextAttention: B=4, S=4096, D=512.
// Round 11: qkt8 retuned for the default 128-reg/wave cap (1024-thr assumption,
// __launch_bounds__ banned): 1024 threads = 16 waves (4Mx4N), wave tile 64x64,
// acc[4][4] (64 AGPR) + af/bf (32 VGPR) fits like pv does. Same verified
// 256^2 8-phase schedule, st-swizzle, XCD swizzle. vmcnt discipline tightened:
// counted vmcnt(4) at ph1-end AND ph3-end (r10 left t+1.k1 unfenced).
// proj_fast / pv_kernel / convert unchanged (m97-style core).
// BANNED: __launch_bounds__ (crash-assoc rounds 1-3). All grids 1-D.

#define BDIM 4
#define SDIM 4096
#define DDIM 512
#define MROWS (BDIM * SDIM)  // 16384
#define XB_ELEMS ((size_t)MROWS * DDIM)        // 8388608
#define W_ELEMS ((size_t)DDIM * DDIM)          // 262144
#define KT8 8                                  // 512 / 64 K-tiles (qkt8)

typedef short short8_t __attribute__((ext_vector_type(8)));
typedef short short4_t __attribute__((ext_vector_type(4)));
typedef float float4_t __attribute__((ext_vector_type(4)));

typedef __attribute__((address_space(1))) void gvoid_t;
typedef __attribute__((address_space(3))) void lvoid_t;

__device__ __forceinline__ short f2bf(float f) {
    union { float f; uint32_t u; } v; v.f = f;
    uint32_t r = v.u + 0x7FFFu + ((v.u >> 16) & 1u);  // RNE
    return (short)(r >> 16);
}
__device__ __forceinline__ float bf2f(short s) {
    union { uint32_t u; float f; } v; v.u = ((uint32_t)(uint16_t)s) << 16;
    return v.f;
}

// Storage-dtype vote (proven).
__global__ void detect_kernel(const uint32_t* __restrict__ tok, int* __restrict__ flag) {
    __shared__ int red[256];
    const int tid = threadIdx.x;
    int c = 0;
    for (int i = tid; i < 4096; i += 256) {
        uint32_t e = (tok[i] >> 7) & 0xFFu;
        c += (e >= 105u && e <= 135u) ? 1 : 0;
    }
    red[tid] = c;
    __syncthreads();
    for (int s = 128; s > 0; s >>= 1) {
        if (tid < s) red[tid] += red[tid + s];
        __syncthreads();
    }
    if (tid == 0) *flag = (red[0] > 2048) ? 1 : 0;  // 1 = bf16 storage
}

__global__ void zero_rs_kernel(float* __restrict__ RS) {
    RS[blockIdx.x * 256 + threadIdx.x] = 0.f;
}

// Pre-convert inputs to bf16: dst = Xb[8388608] | W1b | W2b | W3b (262144 ea).
__global__ void convert_kernel(const void* __restrict__ X, const void* __restrict__ W1,
                               const void* __restrict__ W2, const void* __restrict__ W3,
                               short* __restrict__ dst, const int* __restrict__ flagp)
{
    const int bf16in = *flagp;
    const size_t i4 = ((size_t)blockIdx.x * 256 + threadIdx.x) * 4;  // elem index
    const void* src; size_t off;
    if (i4 < XB_ELEMS) { src = X; off = i4; }
    else {
        const size_t j = i4 - XB_ELEMS;
        const int g = (int)(j / W_ELEMS);
        src = (g == 0) ? W1 : (g == 1) ? W2 : W3;
        off = j - (size_t)g * W_ELEMS;
    }
    if (bf16in) {
        *(short4_t*)(dst + i4) = *(const short4_t*)((const short*)src + off);
    } else {
        float4 v = *(const float4*)((const float*)src + off);
        short4_t s = { f2bf(v.x), f2bf(v.y), f2bf(v.z), f2bf(v.w) };
        *(short4_t*)(dst + i4) = s;
    }
}

// ---------------- shared m97-style GEMM core (proj / pv) ----------------
// 128x128 tile, BK=32, unpadded LDS [128][32], staged via global_load_lds
// width=16 (wave-uniform LDS base + lane*16 == row-major 16-row chunk).
__device__ __forceinline__ void gemm_core(
    const short* __restrict__ A, int lda,
    const short* __restrict__ B, int ldb,
    int m0, int n0, int kIters,
    short* As, short* Bs, float4_t acc[4][4])
{
    const int tid = threadIdx.x;
    const int w = tid >> 6, lane = tid & 63, quad = lane >> 4, l16 = lane & 15;
    const int wm = w >> 1, wn = w & 1;
    const int rsub = lane >> 2;          // row within 16-row chunk
    const int col8 = 8 * (lane & 3);     // 8-elem (16B) column chunk

    for (int kk = 0; kk < kIters; ++kk) {
        const int k0 = 32 * kk;
        __syncthreads();
#pragma unroll
        for (int c = 0; c < 2; ++c) {
            const int row = 32 * w + 16 * c + rsub;
            const short* g = A + (size_t)(m0 + row) * lda + k0 + col8;
            __builtin_amdgcn_global_load_lds((const gvoid_t*)g,
                (lvoid_t*)(As + (32 * w + 16 * c) * 32), 16, 0, 0);
        }
#pragma unroll
        for (int c = 0; c < 2; ++c) {
            const int row = 32 * w + 16 * c + rsub;
            const short* g = B + (size_t)(n0 + row) * ldb + k0 + col8;
            __builtin_amdgcn_global_load_lds((const gvoid_t*)g,
                (lvoid_t*)(Bs + (32 * w + 16 * c) * 32), 16, 0, 0);
        }
        __syncthreads();

        short8_t af[4], bfr[4];
#pragma unroll
        for (int mt = 0; mt < 4; ++mt)
            af[mt] = *(const short8_t*)&As[(64 * wm + 16 * mt + l16) * 32 + 8 * quad];
#pragma unroll
        for (int nt = 0; nt < 4; ++nt)
            bfr[nt] = *(const short8_t*)&Bs[(64 * wn + 16 * nt + l16) * 32 + 8 * quad];
#pragma unroll
        for (int mt = 0; mt < 4; ++mt)
#pragma unroll
            for (int nt = 0; nt < 4; ++nt)
                acc[mt][nt] = __builtin_amdgcn_mfma_f32_16x16x32_bf16(af[mt], bfr[nt], acc[mt][nt], 0, 0, 0);
    }
}

// ---------------- proj (all-bf16 via Xb/Wb) ----------------
// g=0: Q = Xb @ W1b^T; g=1: K; g=2: Vt[m=e][n=bs] = W3b @ Xb^T.
__global__ void proj_fast(const short* __restrict__ XbWb, short* __restrict__ QKV)
{
    __shared__ __align__(16) short As[128 * 32];
    __shared__ __align__(16) short Bs[128 * 32];

    const short* Xb = XbWb;
    const int bid = blockIdx.x;
    const int g = bid >> 9;
    const int r = bid & 511;

    const short* Ap; const short* Bp; short* Op;
    int m0, n0, ldo;
    if (g == 2) {
        Ap = XbWb + XB_ELEMS + 2 * W_ELEMS; Bp = Xb;
        Op = QKV + 2 * (size_t)MROWS * DDIM;
        m0 = 128 * (r & 3); n0 = 128 * (r >> 2); ldo = MROWS;   // Vt[e][bs]
    } else {
        Ap = Xb; Bp = XbWb + XB_ELEMS + (size_t)g * W_ELEMS;
        Op = QKV + (size_t)g * MROWS * DDIM;
        m0 = 128 * (r >> 2); n0 = 128 * (r & 3); ldo = DDIM;    // Q/K[bs][e]
    }

    const float4_t z4 = {0.f, 0.f, 0.f, 0.f};
    float4_t acc[4][4];
#pragma unroll
    for (int i = 0; i < 4; ++i)
#pragma unroll
        for (int j = 0; j < 4; ++j) acc[i][j] = z4;

    gemm_core(Ap, DDIM, Bp, DDIM, m0, n0, 16, As, Bs, acc);

    const int tid = threadIdx.x;
    const int w = tid >> 6, lane = tid & 63, quad = lane >> 4, l16 = lane & 15;
    const int wm = w >> 1, wn = w & 1;
#pragma unroll
    for (int mt = 0; mt < 4; ++mt)
#pragma unroll
        for (int nt = 0; nt < 4; ++nt)
#pragma unroll
            for (int rr = 0; rr < 4; ++rr) {
                const int m = m0 + 64 * wm + 16 * mt + 4 * quad + rr;
                const int n = n0 + 64 * wn + 16 * nt + l16;
                Op[(size_t)m * ldo + n] = f2bf(acc[mt][nt][rr]);
            }
}

// ---------------- qkt8: 256^2 8-phase P = exp(sc * Q K^T) + rowsums ----------
// 1024 threads, 16 waves (4Mx4N, wave tile 64x64), BK=64. Dynamic LDS 128KB:
//   region(d, ab, kh) = lds + (d*4 + ab*2 + kh)*8192 shorts  ([256 rows][32 k])
// Per K-tile t (buf d=t&1), 4 phases (ks,nh), 8 MFMA each; stage per phase:
//   ph0: (t+1,A,k1)  ph1: (t+1,B,k1)  ph2: (t+2,A,k0)  ph3: (t+2,B,k0)
// Counted waits (1 load/thread/unit): vmcnt(4) at ph1-end (guards t.k1 for
// ph2) and ph3-end (guards t+1.k0); tail t=KT8-2: ph3 vmcnt(2); t=KT8-1:
// ph1 vmcnt(0), ph3 none. Swizzle: LDS[r][g] = glob[r][g ^ ((r>>1)&3)]
// (granule=8 shorts); stage pre-swizzles source, reads XOR the granule.
__global__ void qkt8_kernel(const short* __restrict__ QKV, short* __restrict__ P,
                            float* __restrict__ RS, int bbase)
{
    extern __shared__ short lds[];

    const int cpx = (int)(gridDim.x >> 3);          // grid % 8 == 0 (bijective)
    const int bid = (int)blockIdx.x;
    const int l = (bid & 7) * cpx + (bid >> 3);     // XCD swizzle (T1)
    const int bb = l >> 8;
    const int r = l & 255;
    const int b = bbase + bb;
    const int m0 = 256 * (r >> 4);
    const int n0 = 256 * (r & 15);

    const short* Qb = QKV + (size_t)b * SDIM * DDIM;
    const short* Kb = QKV + (size_t)MROWS * DDIM + (size_t)b * SDIM * DDIM;

    const int tid = (int)threadIdx.x;
    const int w = tid >> 6, lane = tid & 63;
    const int quad = lane >> 4, l16 = lane & 15;
    const int wm = w >> 2, wn = w & 3;              // 4M x 4N wave grid
    const int xsw = (l16 >> 1) & 3;                 // read swizzle key
    const int sg = (lane & 3) ^ ((lane >> 3) & 3);  // stage source granule
    const int srow = 16 * w + (lane >> 2);          // stage row [0,256)

    // stage one 256x32 k-half unit: 1 global_load_lds(16B) per thread.
    auto STAGE = [&](int u, int ab, int kh) {
        if (u >= KT8) return;
        const short* gb = ab ? Kb : Qb;
        const int r0 = ab ? n0 : m0;
        short* rg = lds + (size_t)((u & 1) * 4 + ab * 2 + kh) * 8192;
        const short* g = gb + (size_t)(r0 + srow) * DDIM + u * 64 + kh * 32 + 8 * sg;
        __builtin_amdgcn_global_load_lds((const gvoid_t*)g,
            (lvoid_t*)(rg + 512 * w), 16, 0, 0);   // wave-uniform base + lane*16
    };

    const float4_t z4 = {0.f, 0.f, 0.f, 0.f};
    float4_t acc[4][4];
#pragma unroll
    for (int i = 0; i < 4; ++i)
#pragma unroll
        for (int j = 0; j < 4; ++j) acc[i][j] = z4;

    // Prologue: tile 0 complete + tile 1 k0 halves; keep only the newest 2
    // (t1.k0) in flight -> tile 0 fully landed.
    STAGE(0, 0, 0); STAGE(0, 1, 0); STAGE(0, 0, 1); STAGE(0, 1, 1);
    STAGE(1, 0, 0); STAGE(1, 1, 0);
    asm volatile("s_waitcnt vmcnt(2)" ::: "memory");
    __builtin_amdgcn_s_barrier();

    short8_t af[4], bf[4];
    for (int t = 0; t < KT8; ++t) {
        const int d = t & 1;
#pragma unroll
        for (int ks = 0; ks < 2; ++ks) {
            const short* Ar = lds + (size_t)(d * 4 + ks) * 8192;
            const short* Br = lds + (size_t)(d * 4 + 2 + ks) * 8192;
#pragma unroll
            for (int nh = 0; nh < 2; ++nh) {
                if (nh == 0) {
#pragma unroll
                    for (int mt = 0; mt < 4; ++mt)
                        af[mt] = *(const short8_t*)&Ar[(64 * wm + 16 * mt + l16) * 32 + 8 * (quad ^ xsw)];
                }
#pragma unroll
                for (int nt = 0; nt < 2; ++nt)
                    bf[2 * nh + nt] = *(const short8_t*)&Br[(64 * wn + 32 * nh + 16 * nt + l16) * 32 + 8 * (quad ^ xsw)];
                const int ph = ks * 2 + nh;
                if (ph == 0)      STAGE(t + 1, 0, 1);
                else if (ph == 1) STAGE(t + 1, 1, 1);
                else if (ph == 2) STAGE(t + 2, 0, 0);
                else              STAGE(t + 2, 1, 0);
                __builtin_amdgcn_s_barrier();
                __builtin_amdgcn_s_setprio(1);
#pragma unroll
                for (int mt = 0; mt < 4; ++mt)
#pragma unroll
                    for (int nt = 0; nt < 2; ++nt)
                        acc[mt][2 * nh + nt] = __builtin_amdgcn_mfma_f32_16x16x32_bf16(
                            af[mt], bf[2 * nh + nt], acc[mt][2 * nh + nt], 0, 0, 0);
                __builtin_amdgcn_s_setprio(0);
                if (ph == 1) {
                    if (t < KT8 - 1) asm volatile("s_waitcnt vmcnt(4)" ::: "memory");
                    else             asm volatile("s_waitcnt vmcnt(0)" ::: "memory");
                } else if (ph == 3) {
                    if (t < KT8 - 2)       asm volatile("s_waitcnt vmcnt(4)" ::: "memory");
                    else if (t == KT8 - 2) asm volatile("s_waitcnt vmcnt(2)" ::: "memory");
                }
                __builtin_amdgcn_s_barrier();
            }
        }
    }

    // Epilogue: P = exp2(acc * kSc) as bf16 + rowsum atomics (same math as r9).
    const float kSc = 1.44269504088896341f * 0.04419417382415922f;  // log2(e)/sqrt(512)
    short* Pb = P + (size_t)bb * SDIM * SDIM;
#pragma unroll
    for (int mt = 0; mt < 4; ++mt)
#pragma unroll
        for (int rr = 0; rr < 4; ++rr) {
            const int q = m0 + 64 * wm + 16 * mt + 4 * quad + rr;
            float sum = 0.f;
#pragma unroll
            for (int nt = 0; nt < 4; ++nt) {
                const float p = exp2f(acc[mt][nt][rr] * kSc);
                const short pb = f2bf(p);
                sum += bf2f(pb);
                Pb[(size_t)q * SDIM + n0 + 64 * wn + 16 * nt + l16] = pb;
            }
            sum += __shfl_xor(sum, 1); sum += __shfl_xor(sum, 2);
            sum += __shfl_xor(sum, 4); sum += __shfl_xor(sum, 8);
            if (l16 == 0) atomicAdd(&RS[(size_t)b * SDIM + q], sum);
        }
}

// ---------------- pv: out = (P @ Vt-rows) / RS ----------------
__global__ void pv_kernel(const short* __restrict__ P, const short* __restrict__ QKV,
                          const float* __restrict__ RS, void* __restrict__ out,
                          const int* __restrict__ flagp, int bbase)
{
    __shared__ __align__(16) short As[128 * 32];
    __shared__ __align__(16) short Bs[128 * 32];

    const int bf16out = *flagp;
    const int bid = blockIdx.x;
    const int bb = bid >> 7;
    const int r = bid & 127;
    const int b = bbase + bb;
    const int m0 = 128 * (r >> 2);
    const int n0 = 128 * (r & 3);

    const short* Pb = P + (size_t)bb * SDIM * SDIM;
    const short* Vt = QKV + 2 * (size_t)MROWS * DDIM + (size_t)b * SDIM;  // rows stride MROWS

    const float4_t z4 = {0.f, 0.f, 0.f, 0.f};
    float4_t acc[4][4];
#pragma unroll
    for (int i = 0; i < 4; ++i)
#pragma unroll
        for (int j = 0; j < 4; ++j) acc[i][j] = z4;

    gemm_core(Pb, SDIM, Vt, MROWS, m0, n0, 128, As, Bs, acc);

    const int tid = threadIdx.x;
    const int w = tid >> 6, lane = tid & 63, quad = lane >> 4, l16 = lane & 15;
    const int wm = w >> 1, wn = w & 1;
#pragma unroll
    for (int mt = 0; mt < 4; ++mt)
#pragma unroll
        for (int rr = 0; rr < 4; ++rr) {
            const size_t grow = (size_t)b * SDIM + m0 + 64 * wm + 16 * mt + 4 * quad + rr;
            const float inv = 1.0f / RS[grow];
#pragma unroll
            for (int nt = 0; nt < 4; ++nt) {
                const int n = n0 + 64 * wn + 16 * nt + l16;
                const float o = acc[mt][nt][rr] * inv;
                if (bf16out) ((short*)out)[grow * DDIM + n] = f2bf(o);
                else         ((float*)out)[grow * DDIM + n] = o;
            }
        }
}

// ---------------- Fallbacks (proven round-6/8 versions) ----------------
__global__ void proj_mfma_legacy(const void* __restrict__ X, const void* __restrict__ W1,
                          const void* __restrict__ W2, const void* __restrict__ W3,
                          short* __restrict__ QKV, const int* __restrict__ flagp)
{
    __shared__ __align__(16) short As[128][40];
    __shared__ __align__(16) short Bs[128][40];

    const int bf16in = *flagp;
    const int bid = blockIdx.x;
    const int g = bid >> 9;
    const int r = bid & 511;

    const void* Ap; const void* Bp; short* Op;
    int m0, n0, ldo;
    if (g == 2) {
        Ap = W3; Bp = X; Op = QKV + 2 * (size_t)MROWS * DDIM;
        m0 = 128 * (r & 3); n0 = 128 * (r >> 2); ldo = MROWS;
    } else {
        Ap = X; Bp = (g == 0) ? W1 : W2; Op = QKV + (size_t)g * MROWS * DDIM;
        m0 = 128 * (r >> 2); n0 = 128 * (r & 3); ldo = DDIM;
    }

    const float* Af = (const float*)Ap;  const float* Bf = (const float*)Bp;
    const short* Ah = (const short*)Ap;  const short* Bh = (const short*)Bp;

    const int tid = threadIdx.x;
    const int w = tid >> 6, lane = tid & 63, quad = lane >> 4, l16 = lane & 15;
    const int wm = w >> 1, wn = w & 1;
    const int rgrp = tid >> 3, cg = tid & 7;

    const float4_t z4 = {0.f, 0.f, 0.f, 0.f};
    float4_t acc[4][4];
#pragma unroll
    for (int i = 0; i < 4; ++i)
#pragma unroll
        for (int j = 0; j < 4; ++j) acc[i][j] = z4;

    for (int kk = 0; kk < 16; ++kk) {
        const int k0 = 32 * kk;
        __syncthreads();
        if (bf16in) {
#pragma unroll
            for (int i = 0; i < 4; ++i) {
                const int row = rgrp + 32 * i;
                *(short4_t*)&As[row][4 * cg] =
                    *(const short4_t*)(Ah + (size_t)(m0 + row) * DDIM + k0 + 4 * cg);
                *(short4_t*)&Bs[row][4 * cg] =
                    *(const short4_t*)(Bh + (size_t)(n0 + row) * DDIM + k0 + 4 * cg);
            }
        } else {
#pragma unroll
            for (int i = 0; i < 4; ++i) {
                const int row = rgrp + 32 * i;
                float4 va = *(const float4*)(Af + (size_t)(m0 + row) * DDIM + k0 + 4 * cg);
                short4_t sa = { f2bf(va.x), f2bf(va.y), f2bf(va.z), f2bf(va.w) };
                *(short4_t*)&As[row][4 * cg] = sa;
                float4 vb = *(const float4*)(Bf + (size_t)(n0 + row) * DDIM + k0 + 4 * cg);
                short4_t sb = { f2bf(vb.x), f2bf(vb.y), f2bf(vb.z), f2bf(vb.w) };
                *(short4_t*)&Bs[row][4 * cg] = sb;
            }
        }
        __syncthreads();

        short8_t af[4], bfr[4];
#pragma unroll
        for (int mt = 0; mt < 4; ++mt)
            af[mt] = *(const short8_t*)&As[64 * wm + 16 * mt + l16][8 * quad];
#pragma unroll
        for (int nt = 0; nt < 4; ++nt)
            bfr[nt] = *(const short8_t*)&Bs[64 * wn + 16 * nt + l16][8 * quad];
#pragma unroll
        for (int mt = 0; mt < 4; ++mt)
#pragma unroll
            for (int nt = 0; nt < 4; ++nt)
                acc[mt][nt] = __builtin_amdgcn_mfma_f32_16x16x32_bf16(af[mt], bfr[nt], acc[mt][nt], 0, 0, 0);
    }

#pragma unroll
    for (int mt = 0; mt < 4; ++mt)
#pragma unroll
        for (int nt = 0; nt < 4; ++nt)
#pragma unroll
            for (int rr = 0; rr < 4; ++rr) {
                const int m = m0 + 64 * wm + 16 * mt + 4 * quad + rr;
                const int n = n0 + 64 * wn + 16 * nt + l16;
                Op[(size_t)m * ldo + n] = f2bf(acc[mt][nt][rr]);
            }
}

__global__ void attn_mfma(const short* __restrict__ QKV, void* __restrict__ out,
                          const int* __restrict__ flagp)
{
    __shared__ __align__(16) short Ks[32][520];
    __shared__ __align__(16) short Ps[32][72];
    __shared__ float rowsum[2][32];

    const int bf16out = *flagp;
    const short* Qb = QKV;
    const short* Kb = QKV + (size_t)MROWS * DDIM;
    const short* Vt = QKV + 2 * (size_t)MROWS * DDIM;

    const int b = blockIdx.x >> 7;
    const int q0 = (blockIdx.x & 127) * 32;
    const int tid = threadIdx.x;
    const int w = tid >> 6, lane = tid & 63, quad = lane >> 4, l16 = lane & 15;
    const int strip = w >> 1, half = w & 1;

    short8_t qf[16];
    {
        const short* qrow = Qb + (size_t)(b * SDIM + q0 + 16 * strip + l16) * DDIM + 8 * quad;
#pragma unroll
        for (int kc = 0; kc < 16; ++kc)
            qf[kc] = *(const short8_t*)(qrow + 32 * kc);
    }

    const float4_t z4 = {0.f, 0.f, 0.f, 0.f};
    float4_t o[2][8];
#pragma unroll
    for (int mt = 0; mt < 2; ++mt)
#pragma unroll
        for (int nt = 0; nt < 8; ++nt) o[mt][nt] = z4;
    float rs[4] = {0.f, 0.f, 0.f, 0.f};

    const float kSc = 1.44269504088896341f * 0.04419417382415922f;

    for (int kt = 0; kt < 128; ++kt) {
        const int kv0 = 32 * kt;
        __syncthreads();
#pragma unroll
        for (int r = 0; r < 8; ++r) {
            const int kv = 8 * w + r;
            short8_t t = *(const short8_t*)(Kb + (size_t)(b * SDIM + kv0 + kv) * DDIM + 8 * lane);
            *(short8_t*)&Ks[kv][8 * lane] = t;
        }
        __syncthreads();

        float4_t sacc = z4;
#pragma unroll
        for (int kc = 0; kc < 16; ++kc) {
            short8_t kf = *(const short8_t*)&Ks[16 * half + l16][32 * kc + 8 * quad];
            sacc = __builtin_amdgcn_mfma_f32_16x16x32_bf16(qf[kc], kf, sacc, 0, 0, 0);
        }

#pragma unroll
        for (int r = 0; r < 4; ++r) {
            const float p = exp2f(sacc[r] * kSc);
            const short pb = f2bf(p);
            rs[r] += bf2f(pb);
            Ps[16 * strip + 4 * quad + r][16 * half + l16] = pb;
        }
        __syncthreads();

        short8_t pa0 = *(const short8_t*)&Ps[l16][8 * quad];
        short8_t pa1 = *(const short8_t*)&Ps[16 + l16][8 * quad];
#pragma unroll
        for (int nt = 0; nt < 8; ++nt) {
            const short* vp = Vt + (size_t)(128 * w + 16 * nt + l16) * MROWS
                            + (b * SDIM + kv0 + 8 * quad);
            short8_t vb = *(const short8_t*)vp;
            o[0][nt] = __builtin_amdgcn_mfma_f32_16x16x32_bf16(pa0, vb, o[0][nt], 0, 0, 0);
            o[1][nt] = __builtin_amdgcn_mfma_f32_16x16x32_bf16(pa1, vb, o[1][nt], 0, 0, 0);
        }
    }

#pragma unroll
    for (int r = 0; r < 4; ++r) {
        float v = rs[r];
        v += __shfl_xor(v, 1); v += __shfl_xor(v, 2);
        v += __shfl_xor(v, 4); v += __shfl_xor(v, 8);
        rs[r] = v;
    }
    if (l16 == 0) {
#pragma unroll
        for (int r = 0; r < 4; ++r)
            rowsum[half][16 * strip + 4 * quad + r] = rs[r];
    }
    __syncthreads();

#pragma unroll
    for (int mt = 0; mt < 2; ++mt)
#pragma unroll
        for (int r = 0; r < 4; ++r) {
            const int q = 16 * mt + 4 * quad + r;
            const float inv = 1.0f / (rowsum[0][q] + rowsum[1][q]);
            const size_t base = (size_t)(b * SDIM + q0 + q) * DDIM + 128 * w + l16;
            if (bf16out) {
                short* orow = (short*)out + base;
#pragma unroll
                for (int nt = 0; nt < 8; ++nt)
                    orow[16 * nt] = f2bf(o[mt][nt][r] * inv);
            } else {
                float* orow = (float*)out + base;
#pragma unroll
                for (int nt = 0; nt < 8; ++nt)
                    orow[16 * nt] = o[mt][nt][r] * inv;
            }
        }
}

__global__ void zero_out_kernel(short* __restrict__ out, int n) {
    int i = blockIdx.x * 256 + threadIdx.x;
    if (i < n) out[i] = 0;
}

extern "C" void kernel_launch(void* const* d_in, const int* in_sizes, int n_in,
                              void* d_out, int out_size, void* d_ws, size_t ws_size,
                              hipStream_t stream) {
    const void* token = d_in[0];
    const void* Wp[3] = { d_in[1], d_in[2], d_in[3] };
    {
        int wi = 0;
        const void* tk = nullptr; const void* ws3[3] = {nullptr, nullptr, nullptr};
        bool ok = true;
        for (int i = 0; i < n_in && i < 4; ++i) {
            if (in_sizes[i] == BDIM * SDIM * DDIM) { if (tk) ok = false; tk = d_in[i]; }
            else if (in_sizes[i] == DDIM * DDIM) { if (wi < 3) ws3[wi++] = d_in[i]; else ok = false; }
            else ok = false;
        }
        if (ok && tk && wi == 3) { token = tk; Wp[0] = ws3[0]; Wp[1] = ws3[1]; Wp[2] = ws3[2]; }
    }

    const size_t qkvBytes = 3 * (size_t)MROWS * DDIM * sizeof(short);  // 48 MB
    const size_t need_base = qkvBytes + 256;
    if (ws_size < need_base) {
        zero_out_kernel<<<(out_size + 255) / 256, 256, 0, stream>>>((short*)d_out, out_size);
        return;
    }

    short* QKV = (short*)d_ws;
    int* flag = (int*)((char*)d_ws + qkvBytes);
    short* P = (short*)((char*)d_ws + need_base);   // P slab; Xb/Wb overlap (dead before qkt)
    const size_t pElems1 = (size_t)SDIM * SDIM;

    int nb = 0;
    for (int cand = 4; cand >= 1; cand >>= 1) {
        const size_t need = need_base + (size_t)cand * pElems1 * sizeof(short)
                          + (size_t)MROWS * sizeof(float);
        if (ws_size >= need) { nb = cand; break; }
    }

    detect_kernel<<<1, 256, 0, stream>>>((const uint32_t*)token, flag);

    if (nb == 0) {
        proj_mfma_legacy<<<dim3(1536), 256, 0, stream>>>(token, Wp[0], Wp[1], Wp[2], QKV, flag);
        attn_mfma<<<dim3(512), 256, 0, stream>>>(QKV, d_out, flag);
        return;
    }

    // One-time: allow 128KB dynamic LDS for qkt8 (host-side, capture-safe).
    static bool qkt8_attr = false;
    if (!qkt8_attr) {
        (void)hipFuncSetAttribute(reinterpret_cast<const void*>(qkt8_kernel),
                                  hipFuncAttributeMaxDynamicSharedMemorySize, 131072);
        qkt8_attr = true;
    }

    // Xb|W1b|W2b|W3b live at the head of the P slab (18.35 MB <= 32 MB min slab).
    short* XbWb = P;
    const size_t cvt4 = (XB_ELEMS + 3 * W_ELEMS) / 4;  // 2293760 lanes
    convert_kernel<<<dim3((unsigned)(cvt4 / 256)), 256, 0, stream>>>(
        token, Wp[0], Wp[1], Wp[2], XbWb, flag);
    proj_fast<<<dim3(1536), 256, 0, stream>>>(XbWb, QKV);

    float* RS = (float*)(P + (size_t)nb * pElems1);
    zero_rs_kernel<<<dim3(MROWS / 256), 256, 0, stream>>>(RS);
    for (int p = 0; p < BDIM / nb; ++p) {
        const int bbase = p * nb;
        qkt8_kernel<<<dim3(nb * 256), 1024, 131072, stream>>>(QKV, P, RS, bbase);
        pv_kernel<<<dim3(nb * 128), 256, 0, stream>>>(P, QKV, RS, d_out, flag, bbase);
    }
}